// Round 1
// baseline (702.111 us; speedup 1.0000x reference)
//
#include <hip/hip_runtime.h>
#include <math.h>

// FM forward: out[b] = sigmoid(bias + sum_k b_vals*w[idx] +
//                              0.5/sum_k(x) * sum_f((sum_k x*V[idx,f])^2 - sum_k x^2*V[idx,f]^2))
// B=8192, K=200, F=128, INPUT_DIM=1e6

#define BATCH 8192
#define KACT  200
#define FDIM  128
#define NTHREADS 256

__global__ __launch_bounds__(NTHREADS, 8) void fm_fwd_kernel(
    const int*   __restrict__ idx,     // [B,K]
    const float* __restrict__ x_vals,  // [B,K]
    const float* __restrict__ b_vals,  // [B,K]
    const float* __restrict__ w,       // [INPUT_DIM]
    const float* __restrict__ V,       // [INPUT_DIM, F]
    const float* __restrict__ bias,    // [1]
    float*       __restrict__ out)     // [B]
{
    const int b   = blockIdx.x;
    const int tid = threadIdx.x;

    __shared__ int   s_idx[KACT];
    __shared__ float s_x[KACT];
    __shared__ float s_b[KACT];
    __shared__ float s_xv[8][FDIM];   // per-slice partial XV
    __shared__ float s_x2[8][FDIM];   // per-slice partial X2V2
    __shared__ float s_red[4][3];     // cross-wave scalar reduce

    // ---- stage idx / x / b for this row (coalesced) ----
    for (int k = tid; k < KACT; k += NTHREADS) {
        s_idx[k] = idx[b * KACT + k];
        s_x[k]   = x_vals[b * KACT + k];
        s_b[k]   = b_vals[b * KACT + k];
    }
    __syncthreads();

    // ---- issue the w-gather early so it overlaps the V loop ----
    float wpart = 0.0f;
    float xpart = 0.0f;
    if (tid < KACT) {
        wpart = s_b[tid] * w[s_idx[tid]];
        xpart = s_x[tid];
    }

    // ---- main gather loop: thread owns float4 of F, strides K by 8 ----
    const int lane_f = tid & 31;   // which float4 within the 128-f row
    const int slice  = tid >> 5;   // 0..7 k-slice
    const float4* __restrict__ V4 = (const float4*)V;  // [INPUT_DIM][32]

    float4 xv = make_float4(0.f, 0.f, 0.f, 0.f);
    float4 x2 = make_float4(0.f, 0.f, 0.f, 0.f);

    #pragma unroll 5
    for (int k = slice; k < KACT; k += 8) {      // 25 iterations each
        const float x   = s_x[k];
        const int   row = s_idx[k];
        const float4 v  = V4[(size_t)row * 32 + lane_f];
        const float xx  = x * x;
        xv.x = fmaf(x, v.x, xv.x);
        xv.y = fmaf(x, v.y, xv.y);
        xv.z = fmaf(x, v.z, xv.z);
        xv.w = fmaf(x, v.w, xv.w);
        x2.x = fmaf(xx, v.x * v.x, x2.x);
        x2.y = fmaf(xx, v.y * v.y, x2.y);
        x2.z = fmaf(xx, v.z * v.z, x2.z);
        x2.w = fmaf(xx, v.w * v.w, x2.w);
    }

    // ---- combine the 8 k-slices BEFORE squaring ----
    *(float4*)&s_xv[slice][lane_f * 4] = xv;
    *(float4*)&s_x2[slice][lane_f * 4] = x2;
    __syncthreads();

    float part = 0.0f;
    if (tid < FDIM) {
        float S = 0.f, T = 0.f;
        #pragma unroll
        for (int s = 0; s < 8; ++s) {
            S += s_xv[s][tid];
            T += s_x2[s][tid];
        }
        part = S * S - T;   // XV[f]^2 - X2V2[f]
    }

    // ---- block reduce: part (f-sum), wpart (Xw), xpart (sum x) ----
    float v1 = part, v2 = wpart, v3 = xpart;
    #pragma unroll
    for (int off = 32; off > 0; off >>= 1) {
        v1 += __shfl_xor(v1, off);
        v2 += __shfl_xor(v2, off);
        v3 += __shfl_xor(v3, off);
    }
    const int wave = tid >> 6;
    const int lane = tid & 63;
    if (lane == 0) {
        s_red[wave][0] = v1;
        s_red[wave][1] = v2;
        s_red[wave][2] = v3;
    }
    __syncthreads();

    if (tid == 0) {
        float P = 0.f, W = 0.f, X = 0.f;
        #pragma unroll
        for (int i = 0; i < 4; ++i) {
            P += s_red[i][0];
            W += s_red[i][1];
            X += s_red[i][2];
        }
        const float z = bias[0] + W + 0.5f * (P / X);
        out[b] = 1.0f / (1.0f + expf(-z));
    }
}

extern "C" void kernel_launch(void* const* d_in, const int* in_sizes, int n_in,
                              void* d_out, int out_size, void* d_ws, size_t ws_size,
                              hipStream_t stream) {
    const int*   idx    = (const int*)  d_in[0];
    const float* x_vals = (const float*)d_in[1];
    const float* b_vals = (const float*)d_in[2];
    const float* w      = (const float*)d_in[3];
    const float* V      = (const float*)d_in[4];
    const float* bias   = (const float*)d_in[5];
    float* out = (float*)d_out;

    fm_fwd_kernel<<<BATCH, NTHREADS, 0, stream>>>(idx, x_vals, b_vals, w, V, bias, out);
}